// Round 9
// baseline (214.246 us; speedup 1.0000x reference)
//
#include <hip/hip_runtime.h>
#include <hip/hip_bf16.h>

#define NN 10000
#define EE 65536

using short8  = __attribute__((ext_vector_type(8))) short;
using u16x8   = __attribute__((ext_vector_type(8))) unsigned short;
using float4v = __attribute__((ext_vector_type(4))) float;

__device__ __forceinline__ unsigned short f2b(float f){
  union { float f; unsigned int u; } v; v.f = f;
  unsigned int u = v.u;
  unsigned int r = (u + 0x7fff + ((u >> 16) & 1)) >> 16;  // RNE
  return (unsigned short)r;
}

__device__ __forceinline__ short8 ntload(const unsigned short* p){
  return __builtin_nontemporal_load((const short8*)p);
}

// ---------------- tiled-fragment layout (row-major tile interior) ----------------
// K (A-side) and Bt (B-side) stored as 1024-B tiles = one MFMA wave-fragment:
//   tile index = rowtile*KT32 + k32 ; within tile, elem (row,kk) at short row*32+kk.
// GEMM lane l reads its granule at (l&15)*32 + (l>>4)*8 shorts.

// ---------------- prep: zero cnt + permB x2 ----------------

__device__ __forceinline__ void do_permB(int idx, const float* __restrict__ w2,
                                         unsigned short* __restrict__ Bt,
                                         int cin, int s /*log2(KT32)*/, int cb /*log2(cin)*/){
  int tile   = idx >> 9;
  int within = idx & 511;
  int ot  = tile >> s;
  int k32 = tile & ((1<<s)-1);
  int kk   = within & 31;
  int orow = within >> 5;
  int o = ot*16 + orow;
  int k = k32*32 + kk;
  int m = k >> cb;
  int i = k & (cin-1);
  Bt[idx] = f2b(w2[(size_t)m*(cin*64) + i*64 + o]);
}

__global__ __launch_bounds__(256) void k_prep(
    const float* __restrict__ w2a, unsigned short* __restrict__ Bt1,
    const float* __restrict__ w2b, unsigned short* __restrict__ Bt2,
    int* __restrict__ cnt){
  int b = blockIdx.x;
  int t = threadIdx.x;
  if(b < 40){
    int i = b*256 + t;
    if(i < NN) cnt[i] = 0;
  } else if(b < 296){
    do_permB((b-40)*256 + t, w2a, Bt1, 16, 5, 4);
  } else {
    do_permB((b-296)*256 + t, w2b, Bt2, 64, 7, 6);
  }
}

// ---------------- CSR build ----------------

__global__ void k_hist(const int* __restrict__ dst, int* __restrict__ cnt){
  int e = blockIdx.x*256 + threadIdx.x;
  if(e < EE) atomicAdd(&cnt[dst[e]], 1);
}

__global__ __launch_bounds__(1024) void k_scan(const int* __restrict__ cnt, int* __restrict__ offs, int* __restrict__ cursor){
  const int T = 1024, PER = (NN + T - 1)/T; // 10
  int tid = threadIdx.x;
  int base = tid*PER;
  int local[PER];
  int s = 0;
  #pragma unroll
  for(int j=0;j<PER;j++){
    int i = base+j;
    int v = (i<NN)? cnt[i] : 0;
    local[j] = s;
    s += v;
  }
  int lane = tid & 63, wv = tid >> 6;
  int val = s;
  #pragma unroll
  for(int o=1;o<64;o<<=1){
    int u = __shfl_up(val, o, 64);
    if(lane >= o) val += u;
  }
  __shared__ int wsum[16];
  if(lane==63) wsum[wv] = val;
  __syncthreads();
  if(tid==0){
    int acc=0;
    #pragma unroll
    for(int i=0;i<16;i++){ int t2=wsum[i]; wsum[i]=acc; acc+=t2; }
  }
  __syncthreads();
  int thr_excl = wsum[wv] + (val - s);
  #pragma unroll
  for(int j=0;j<PER;j++){
    int i = base+j;
    if(i<NN){ int e = thr_excl + local[j]; offs[i]=e; cursor[i]=e; }
  }
  if(tid == T-1) offs[NN] = thr_excl + s;
}

__global__ void k_scatter(const int* __restrict__ dst, const int* __restrict__ src,
                          int* __restrict__ cursor, int2* __restrict__ elist2){
  int e = blockIdx.x*256 + threadIdx.x;
  if(e < EE){ int p = atomicAdd(&cursor[dst[e]], 1); elist2[p] = make_int2(e, src[e]); }
}

// ---------------- per-dst rank-1 accumulation, cin=16 ----------------
// 4 INDEPENDENT waves per 256-thread block, one node each (no barriers, no LDS):
// cross-lane h broadcast via __shfl (ds_bpermute, wave-local, ordering-safe).

__global__ __launch_bounds__(256) void k_accK1(const float* __restrict__ x,
    const int* __restrict__ offs, const int2* __restrict__ elist2,
    const float* __restrict__ ea, const float* __restrict__ w1, const float* __restrict__ b1,
    unsigned short* __restrict__ K1, float* __restrict__ XS, int v0){
  int tid = threadIdx.x;
  int wv = tid >> 6;
  int r = blockIdx.x*4 + wv;     // local row within chunk
  int v = v0 + r;
  int L = tid & 63;
  int cg = L & 3, mg = L >> 2;
  int i0 = cg << 2;
  float w1c0 = w1[L], w1c1 = w1[64+L], w1c2 = w1[128+L], w1c3 = w1[192+L];
  float b1c = b1[L];
  float acc[4][4];
  #pragma unroll
  for(int j=0;j<4;j++)
    #pragma unroll
    for(int c=0;c<4;c++) acc[j][c]=0.f;
  float4 xs = make_float4(0.f,0.f,0.f,0.f);
  int p0 = offs[v], p1 = offs[v+1];
  float4 a_nxt = make_float4(0.f,0.f,0.f,0.f);
  float4 x_nxt = make_float4(0.f,0.f,0.f,0.f);
  if(p0 < p1){
    int2 es = elist2[p0];
    a_nxt = *(const float4*)(ea + (size_t)es.x*4);
    x_nxt = *(const float4*)(x + (size_t)es.y*16 + i0);
  }
  for(int p=p0;p<p1;p++){
    float4 xv = x_nxt;
    float4 av = a_nxt;
    float hv = fmaxf(b1c + av.x*w1c0 + av.y*w1c1 + av.z*w1c2 + av.w*w1c3, 0.f);
    if(p+1<p1){
      int2 es = elist2[p+1];
      a_nxt = *(const float4*)(ea + (size_t)es.x*4);
      x_nxt = *(const float4*)(x + (size_t)es.y*16 + i0);
    }
    xs.x += xv.x; xs.y += xv.y; xs.z += xv.z; xs.w += xv.w;
    #pragma unroll
    for(int j=0;j<4;j++){
      float hm = __shfl(hv, mg + 16*j, 64);
      acc[j][0] += hm*xv.x; acc[j][1] += hm*xv.y;
      acc[j][2] += hm*xv.z; acc[j][3] += hm*xv.w;
    }
  }
  // tiled store: k = m*16 + cg*4 + c -> k32 = m>>1, kk = (m&1)*16 + cg*4 + c
  int rt = r >> 4, lrow = r & 15;
  #pragma unroll
  for(int j=0;j<4;j++){
    int m = mg + 16*j;
    size_t sidx = ((size_t)(rt*32 + (m>>1)))*512
                + (size_t)lrow*32 + (m&1)*16 + cg*4;
    ushort4 u;
    u.x=f2b(acc[j][0]); u.y=f2b(acc[j][1]); u.z=f2b(acc[j][2]); u.w=f2b(acc[j][3]);
    *(ushort4*)(K1 + sidx) = u;
  }
  if(mg==0) *(float4*)(XS + (size_t)v*64 + i0) = xs;
}

// ---------------- per-dst rank-1 accumulation, cin=64 ----------------
// same structure: 4 independent waves/block, shuffle-based h broadcast.

__global__ __launch_bounds__(256) void k_accK2(const float* __restrict__ x1,
    const int* __restrict__ offs, const int2* __restrict__ elist2,
    const float* __restrict__ ea, const float* __restrict__ w1, const float* __restrict__ b1,
    unsigned short* __restrict__ K, float* __restrict__ XS, int v0){
  int tid = threadIdx.x;
  int wv = tid >> 6;
  int r = blockIdx.x*4 + wv;
  int v = v0 + r;
  int L = tid & 63;
  int cg = L & 7, mg = L >> 3;
  int i0 = cg << 3;
  float w1c0 = w1[L], w1c1 = w1[64+L], w1c2 = w1[128+L], w1c3 = w1[192+L];
  float b1c = b1[L];
  float acc[8][8];
  #pragma unroll
  for(int j=0;j<8;j++)
    #pragma unroll
    for(int c=0;c<8;c++) acc[j][c]=0.f;
  float4 xs0 = make_float4(0.f,0.f,0.f,0.f);
  float4 xs1 = make_float4(0.f,0.f,0.f,0.f);
  int p0 = offs[v], p1 = offs[v+1];
  float4 a_nxt = make_float4(0.f,0.f,0.f,0.f);
  float4 x_nxt0 = make_float4(0.f,0.f,0.f,0.f);
  float4 x_nxt1 = make_float4(0.f,0.f,0.f,0.f);
  if(p0 < p1){
    int2 es = elist2[p0];
    a_nxt = *(const float4*)(ea + (size_t)es.x*4);
    const float* xr = x1 + (size_t)es.y*64 + i0;
    x_nxt0 = *(const float4*)xr;
    x_nxt1 = *(const float4*)(xr+4);
  }
  for(int p=p0;p<p1;p++){
    float4 xv0 = x_nxt0, xv1 = x_nxt1;
    float4 av = a_nxt;
    float hv = fmaxf(b1c + av.x*w1c0 + av.y*w1c1 + av.z*w1c2 + av.w*w1c3, 0.f);
    if(p+1<p1){
      int2 es = elist2[p+1];
      a_nxt = *(const float4*)(ea + (size_t)es.x*4);
      const float* xr = x1 + (size_t)es.y*64 + i0;
      x_nxt0 = *(const float4*)xr;
      x_nxt1 = *(const float4*)(xr+4);
    }
    xs0.x += xv0.x; xs0.y += xv0.y; xs0.z += xv0.z; xs0.w += xv0.w;
    xs1.x += xv1.x; xs1.y += xv1.y; xs1.z += xv1.z; xs1.w += xv1.w;
    #pragma unroll
    for(int j=0;j<8;j++){
      float hm = __shfl(hv, mg*8 + j, 64);
      acc[j][0] += hm*xv0.x; acc[j][1] += hm*xv0.y;
      acc[j][2] += hm*xv0.z; acc[j][3] += hm*xv0.w;
      acc[j][4] += hm*xv1.x; acc[j][5] += hm*xv1.y;
      acc[j][6] += hm*xv1.z; acc[j][7] += hm*xv1.w;
    }
  }
  // tiled store: k = m*64 + cg*8 + c -> k32 = m*2 + (cg>>2), kk = (cg&3)*8 + c
  int rt = r >> 4, lrow = r & 15;
  #pragma unroll
  for(int j=0;j<8;j++){
    int m = mg*8 + j;
    size_t sidx = ((size_t)(rt*128 + m*2 + (cg>>2)))*512
                + (size_t)lrow*32 + (cg&3)*8;
    u16x8 u;
    #pragma unroll
    for(int c=0;c<8;c++) u[c] = f2b(acc[j][c]);
    *(u16x8*)(K + sidx) = u;
  }
  if(mg==0){
    *(float4*)(XS + (size_t)v*64 + i0)     = xs0;
    *(float4*)(XS + (size_t)v*64 + i0 + 4) = xs1;
  }
}

// ---------------- split-K GEMM, 128 rows/block, B-slice staged in LDS ----------------

template<int KT32, int TSTEPS>
__global__ __launch_bounds__(512) void k_gemmS(const unsigned short* __restrict__ A,
    const unsigned short* __restrict__ Bt, float* __restrict__ P,
    int ntiles, int rowsChunk){
  __shared__ unsigned short Bs[4*TSTEPS*512];
  int tid = threadIdx.x;
  int lane = tid & 63;
  int w = tid >> 6;
  int s = blockIdx.y;
  int kbase = s*TSTEPS;

  constexpr int NT = 4*TSTEPS;
  constexpr int PERW = NT/8;
  #pragma unroll
  for(int it=0; it<PERW; it++){
    int g = w*PERW + it;
    int ct = g / TSTEPS, t = g - ct*TSTEPS;
    *(short8*)(Bs + (size_t)g*512 + lane*8) =
        *(const short8*)(Bt + (((size_t)ct*KT32 + kbase + t) << 9) + lane*8);
  }
  __syncthreads();

  int lrt = blockIdx.x*8 + w;
  if(lrt >= ntiles) return;

  int lperm = (lane & 15)*32 + (lane >> 4)*8;
  const unsigned short* Ap = A + (((size_t)lrt*KT32 + kbase) << 9) + lperm;
  const unsigned short* BsL = Bs + lperm;

  float4v acc0{}, acc1{}, acc2{}, acc3{};
  short8 ab[4];
  #pragma unroll
  for(int t=0;t<4;t++) ab[t] = ntload(Ap + t*512);

  #pragma unroll
  for(int t=0;t<TSTEPS;t++){
    short8 a  = ab[t&3];
    short8 b0 = *(const short8*)(BsL + (0*TSTEPS+t)*512);
    short8 b1 = *(const short8*)(BsL + (1*TSTEPS+t)*512);
    short8 b2 = *(const short8*)(BsL + (2*TSTEPS+t)*512);
    short8 b3 = *(const short8*)(BsL + (3*TSTEPS+t)*512);
    acc0 = __builtin_amdgcn_mfma_f32_16x16x32_bf16(a, b0, acc0, 0,0,0);
    acc1 = __builtin_amdgcn_mfma_f32_16x16x32_bf16(a, b1, acc1, 0,0,0);
    acc2 = __builtin_amdgcn_mfma_f32_16x16x32_bf16(a, b2, acc2, 0,0,0);
    acc3 = __builtin_amdgcn_mfma_f32_16x16x32_bf16(a, b3, acc3, 0,0,0);
    if(t+4 < TSTEPS) ab[t&3] = ntload(Ap + (t+4)*512);
  }

  int lrow = lane & 15, quad = lane >> 4;
  float* Pr = P + ((size_t)s*rowsChunk + lrt*16 + quad*4)*64 + lrow;
  #pragma unroll
  for(int reg=0;reg<4;reg++){
    Pr[(size_t)reg*64 +  0] = acc0[reg];
    Pr[(size_t)reg*64 + 16] = acc1[reg];
    Pr[(size_t)reg*64 + 32] = acc2[reg];
    Pr[(size_t)reg*64 + 48] = acc3[reg];
  }
}

// ---------------- split reduction + epilogue (layer1) ----------------

template<int CIN, int SPLIT>
__global__ __launch_bounds__(256) void k_reduce_ep(const float* __restrict__ P, int rows, int v0,
    const float* __restrict__ XS, const float* __restrict__ b2, const float* __restrict__ xprev,
    const float* __restrict__ root, const float* __restrict__ bias, const int* __restrict__ offs,
    float* __restrict__ out){
  int idx = blockIdx.x*256 + threadIdx.x;
  if(idx >= rows*16) return;
  int r = idx >> 4, og = (idx & 15) << 2;
  int v = v0 + r;

  float4 s = make_float4(0.f,0.f,0.f,0.f);
  #pragma unroll
  for(int z=0; z<SPLIT; z++){
    float4 p = *(const float4*)(P + ((size_t)z*rows + r)*64 + og);
    s.x += p.x; s.y += p.y; s.z += p.z; s.w += p.w;
  }
  #pragma unroll
  for(int i=0;i<CIN;i++){
    float xsv = XS[(size_t)v*64 + i];
    float4 b = *(const float4*)(b2 + i*64 + og);
    s.x += xsv*b.x; s.y += xsv*b.y; s.z += xsv*b.z; s.w += xsv*b.w;
  }
  float4 rt = make_float4(0.f,0.f,0.f,0.f);
  #pragma unroll
  for(int i=0;i<CIN;i++){
    float xv = xprev[(size_t)v*CIN + i];
    float4 wv = *(const float4*)(root + i*64 + og);
    rt.x += xv*wv.x; rt.y += xv*wv.y; rt.z += xv*wv.z; rt.w += xv*wv.w;
  }
  float c = (float)(offs[v+1]-offs[v]); c = fmaxf(c, 1.f);
  float inv = 1.f/c;
  float4 bi = *(const float4*)(bias + og);
  float4 o;
  o.x = fmaxf(s.x*inv + rt.x + bi.x, 0.f);
  o.y = fmaxf(s.y*inv + rt.y + bi.y, 0.f);
  o.z = fmaxf(s.z*inv + rt.z + bi.z, 0.f);
  o.w = fmaxf(s.w*inv + rt.w + bi.w, 0.f);
  *(float4*)(out + (size_t)v*64 + og) = o;
}

// ---------------- layer-2 reduction + epilogue + fused readout ----------------

template<int SPLIT>
__global__ __launch_bounds__(256) void k_red2_ro(const float* __restrict__ P, int rows, int v0,
    const float* __restrict__ XS, const float* __restrict__ b2, const float* __restrict__ x1,
    const float* __restrict__ root, const float* __restrict__ bias, const int* __restrict__ offs,
    const float* __restrict__ lw1, const float* __restrict__ lb1,
    const float* __restrict__ lw2, const float* __restrict__ lb2,
    float* __restrict__ out){
  __shared__ float row[16][68];
  __shared__ float hjs[16][8];
  int tid = threadIdx.x;
  int idx = blockIdx.x*256 + tid;
  int r = idx >> 4, og = (idx & 15) << 2;
  int n = tid >> 4;
  int nbase = blockIdx.x*16;
  int ninblk = rows - nbase; if(ninblk > 16) ninblk = 16;

  float4 o = make_float4(0.f,0.f,0.f,0.f);
  if(r < rows){
    int vg = v0 + r;
    float4 s = make_float4(0.f,0.f,0.f,0.f);
    #pragma unroll
    for(int z=0; z<SPLIT; z++){
      float4 p = *(const float4*)(P + ((size_t)z*rows + r)*64 + og);
      s.x += p.x; s.y += p.y; s.z += p.z; s.w += p.w;
    }
    #pragma unroll
    for(int i=0;i<64;i++){
      float xsv = XS[(size_t)vg*64 + i];
      float4 b = *(const float4*)(b2 + i*64 + og);
      s.x += xsv*b.x; s.y += xsv*b.y; s.z += xsv*b.z; s.w += xsv*b.w;
    }
    float4 rt = make_float4(0.f,0.f,0.f,0.f);
    #pragma unroll
    for(int i=0;i<64;i++){
      float xv = x1[(size_t)vg*64 + i];
      float4 wv = *(const float4*)(root + i*64 + og);
      rt.x += xv*wv.x; rt.y += xv*wv.y; rt.z += xv*wv.z; rt.w += xv*wv.w;
    }
    float c = (float)(offs[vg+1]-offs[vg]); c = fmaxf(c, 1.f);
    float inv = 1.f/c;
    float4 bi = *(const float4*)(bias + og);
    o.x = fmaxf(s.x*inv + rt.x + bi.x, 0.f);
    o.y = fmaxf(s.y*inv + rt.y + bi.y, 0.f);
    o.z = fmaxf(s.z*inv + rt.z + bi.z, 0.f);
    o.w = fmaxf(s.w*inv + rt.w + bi.w, 0.f);
  }
  *(float4*)&row[n][og] = o;
  __syncthreads();
  if(tid < 128){
    int n2 = tid >> 3, j = tid & 7;
    if(n2 < ninblk){
      float a = lb1[j];
      #pragma unroll
      for(int i=0;i<64;i++) a += row[n2][i]*lw1[i*8+j];
      hjs[n2][j] = fmaxf(a, 0.f)*lw2[j];
    }
  }
  __syncthreads();
  if(tid < 16 && tid < ninblk){
    float s = lb2[0];
    #pragma unroll
    for(int j=0;j<8;j++) s += hjs[tid][j];
    out[v0 + nbase + tid] = s;
  }
}

// ---------------- host ----------------

extern "C" void kernel_launch(void* const* d_in, const int* in_sizes, int n_in,
                              void* d_out, int out_size, void* d_ws, size_t ws_size,
                              hipStream_t stream) {
  const float* x      = (const float*)d_in[0];
  const int*   ei     = (const int*)d_in[1];
  const float* ea     = (const float*)d_in[2];
  const float* nn1_w1 = (const float*)d_in[3];
  const float* nn1_b1 = (const float*)d_in[4];
  const float* nn1_w2 = (const float*)d_in[5];
  const float* nn1_b2 = (const float*)d_in[6];
  const float* root1  = (const float*)d_in[7];
  const float* bias1  = (const float*)d_in[8];
  const float* nn2_w1 = (const float*)d_in[9];
  const float* nn2_b1 = (const float*)d_in[10];
  const float* nn2_w2 = (const float*)d_in[11];
  const float* nn2_b2 = (const float*)d_in[12];
  const float* root2  = (const float*)d_in[13];
  const float* bias2  = (const float*)d_in[14];
  const float* lin1_w = (const float*)d_in[15];
  const float* lin1_b = (const float*)d_in[16];
  const float* lin2_w = (const float*)d_in[17];
  const float* lin2_b = (const float*)d_in[18];
  float* out = (float*)d_out;

  const int* srcIdx = ei;
  const int* dstIdx = ei + EE;

  char* w = (char*)d_ws;
  size_t off = 0;
  auto alloc = [&](size_t bytes)->void*{
    void* p = w + off;
    off = (off + bytes + 255) & ~(size_t)255;
    return p;
  };
  int*            cnt    = (int*)           alloc((size_t)NN*4);
  int*            offs   = (int*)           alloc((size_t)(NN+1)*4);
  int*            cursor = (int*)           alloc((size_t)NN*4);
  int2*           elist2 = (int2*)          alloc((size_t)EE*8);
  float*          XS     = (float*)         alloc((size_t)NN*64*4);
  float*          x1     = (float*)         alloc((size_t)NN*64*4);
  unsigned short* Bt1    = (unsigned short*)alloc((size_t)64*1024*2);
  unsigned short* Bt2    = (unsigned short*)alloc((size_t)64*4096*2);
  size_t fixedBytes = off;
  size_t R = (ws_size > fixedBytes) ? (ws_size - fixedBytes) : 0;

  const int S1 = 4, S2 = 8;
  size_t needSingle = (size_t)(NN/16)*128*1024 + (size_t)S2*NN*64*4;
  bool single = (R >= needSingle + 4096);

  k_prep   <<<1320, 256, 0, stream>>>(nn1_w2, Bt1, nn2_w2, Bt2, cnt);
  k_hist   <<<(EE+255)/256, 256, 0, stream>>>(dstIdx, cnt);
  k_scan   <<<1, 1024, 0, stream>>>(cnt, offs, cursor);
  k_scatter<<<(EE+255)/256, 256, 0, stream>>>(dstIdx, srcIdx, cursor, elist2);

  if(single){
    unsigned short* Kbuf = (unsigned short*)(w + off);
    float* P = (float*)(w + off + (size_t)(NN/16)*128*1024);
    int ntiles = NN/16;                 // 625
    int gx = (ntiles + 7)/8;            // 79

    k_accK1 <<<NN/4, 256, 0, stream>>>(x, offs, elist2, ea, nn1_w1, nn1_b1, Kbuf, XS, 0);
    k_gemmS<32,8> <<<dim3(gx, S1), 512, 0, stream>>>(Kbuf, Bt1, P, ntiles, NN);
    k_reduce_ep<16,S1><<<(NN*16+255)/256, 256, 0, stream>>>(P, NN, 0, XS, nn1_b2, x,
                                                             root1, bias1, offs, x1);
    k_accK2 <<<NN/4, 256, 0, stream>>>(x1, offs, elist2, ea, nn2_w1, nn2_b1, Kbuf, XS, 0);
    k_gemmS<128,16><<<dim3(gx, S2), 512, 0, stream>>>(Kbuf, Bt2, P, ntiles, NN);
    k_red2_ro<S2><<<(NN+15)/16, 256, 0, stream>>>(P, NN, 0, XS, nn2_b2, x1, root2, bias2, offs,
                                                   lin1_w, lin1_b, lin2_w, lin2_b, out);
  } else {
    long long C2 = (long long)(R / (8192 + S2*256));
    long long C1 = (long long)(R / (2048 + S1*256));
    if(C2 > NN) C2 = NN; if(C1 > NN) C1 = NN;
    C2 &= ~127LL; C1 &= ~127LL;
    if(C2 < 128) C2 = 128; if(C1 < 128) C1 = 128;
    unsigned short* Kbuf = (unsigned short*)(w + off);
    {
      float* P = (float*)(w + off + (size_t)C1*2048);
      for(long long v0=0; v0<NN; v0+=C1){
        int rows = (int)((NN - v0 < C1) ? (NN - v0) : C1);
        int nt = rows/16, gx = (nt + 7)/8;
        k_accK1<<<rows/4, 256, 0, stream>>>(x, offs, elist2, ea, nn1_w1, nn1_b1, Kbuf, XS, (int)v0);
        k_gemmS<32,8><<<dim3(gx, S1), 512, 0, stream>>>(Kbuf, Bt1, P, nt, rows);
        k_reduce_ep<16,S1><<<(rows*16+255)/256, 256, 0, stream>>>(P, rows, (int)v0, XS, nn1_b2, x,
                                                                   root1, bias1, offs, x1);
      }
    }
    {
      float* P = (float*)(w + off + (size_t)C2*8192);
      for(long long v0=0; v0<NN; v0+=C2){
        int rows = (int)((NN - v0 < C2) ? (NN - v0) : C2);
        int nt = rows/16, gx = (nt + 7)/8;
        k_accK2<<<rows/4, 256, 0, stream>>>(x1, offs, elist2, ea, nn2_w1, nn2_b1, Kbuf, XS, (int)v0);
        k_gemmS<128,16><<<dim3(gx, S2), 512, 0, stream>>>(Kbuf, Bt2, P, nt, rows);
        k_red2_ro<S2><<<(rows+15)/16, 256, 0, stream>>>(P, rows, (int)v0, XS, nn2_b2, x1,
                                                         root2, bias2, offs,
                                                         lin1_w, lin1_b, lin2_w, lin2_b, out);
      }
    }
  }
}

// Round 10
// 206.670 us; speedup vs baseline: 1.0367x; 1.0367x over previous
//
#include <hip/hip_runtime.h>
#include <hip/hip_bf16.h>

#define NN 10000
#define EE 65536

using short8  = __attribute__((ext_vector_type(8))) short;
using u16x8   = __attribute__((ext_vector_type(8))) unsigned short;
using float4v = __attribute__((ext_vector_type(4))) float;

__device__ __forceinline__ unsigned short f2b(float f){
  union { float f; unsigned int u; } v; v.f = f;
  unsigned int u = v.u;
  unsigned int r = (u + 0x7fff + ((u >> 16) & 1)) >> 16;  // RNE
  return (unsigned short)r;
}

__device__ __forceinline__ short8 ntload(const unsigned short* p){
  return __builtin_nontemporal_load((const short8*)p);
}

// ---------------- tiled-fragment layout (row-major tile interior) ----------------
// K (A-side) and Bt (B-side) stored as 1024-B tiles = one MFMA wave-fragment:
//   tile index = rowtile*KT32 + k32 ; within tile, elem (row,kk) at short row*32+kk.
// GEMM lane l reads its granule at (l&15)*32 + (l>>4)*8 shorts.

// ---------------- prep: zero cnt + permB x2 ----------------

__device__ __forceinline__ void do_permB(int idx, const float* __restrict__ w2,
                                         unsigned short* __restrict__ Bt,
                                         int cin, int s /*log2(KT32)*/, int cb /*log2(cin)*/){
  int tile   = idx >> 9;
  int within = idx & 511;
  int ot  = tile >> s;
  int k32 = tile & ((1<<s)-1);
  int kk   = within & 31;
  int orow = within >> 5;
  int o = ot*16 + orow;
  int k = k32*32 + kk;
  int m = k >> cb;
  int i = k & (cin-1);
  Bt[idx] = f2b(w2[(size_t)m*(cin*64) + i*64 + o]);
}

__global__ __launch_bounds__(256) void k_prep(
    const float* __restrict__ w2a, unsigned short* __restrict__ Bt1,
    const float* __restrict__ w2b, unsigned short* __restrict__ Bt2,
    int* __restrict__ cnt){
  int b = blockIdx.x;
  int t = threadIdx.x;
  if(b < 40){
    int i = b*256 + t;
    if(i < NN) cnt[i] = 0;
  } else if(b < 296){
    do_permB((b-40)*256 + t, w2a, Bt1, 16, 5, 4);
  } else {
    do_permB((b-296)*256 + t, w2b, Bt2, 64, 7, 6);
  }
}

// ---------------- CSR build ----------------

__global__ void k_hist(const int* __restrict__ dst, int* __restrict__ cnt){
  int e = blockIdx.x*256 + threadIdx.x;
  if(e < EE) atomicAdd(&cnt[dst[e]], 1);
}

__global__ __launch_bounds__(1024) void k_scan(const int* __restrict__ cnt, int* __restrict__ offs, int* __restrict__ cursor){
  const int T = 1024, PER = (NN + T - 1)/T; // 10
  int tid = threadIdx.x;
  int base = tid*PER;
  int local[PER];
  int s = 0;
  #pragma unroll
  for(int j=0;j<PER;j++){
    int i = base+j;
    int v = (i<NN)? cnt[i] : 0;
    local[j] = s;
    s += v;
  }
  int lane = tid & 63, wv = tid >> 6;
  int val = s;
  #pragma unroll
  for(int o=1;o<64;o<<=1){
    int u = __shfl_up(val, o, 64);
    if(lane >= o) val += u;
  }
  __shared__ int wsum[16];
  if(lane==63) wsum[wv] = val;
  __syncthreads();
  if(tid==0){
    int acc=0;
    #pragma unroll
    for(int i=0;i<16;i++){ int t2=wsum[i]; wsum[i]=acc; acc+=t2; }
  }
  __syncthreads();
  int thr_excl = wsum[wv] + (val - s);
  #pragma unroll
  for(int j=0;j<PER;j++){
    int i = base+j;
    if(i<NN){ int e = thr_excl + local[j]; offs[i]=e; cursor[i]=e; }
  }
  if(tid == T-1) offs[NN] = thr_excl + s;
}

__global__ void k_scatter(const int* __restrict__ dst, const int* __restrict__ src,
                          int* __restrict__ cursor, int2* __restrict__ elist2){
  int e = blockIdx.x*256 + threadIdx.x;
  if(e < EE){ int p = atomicAdd(&cursor[dst[e]], 1); elist2[p] = make_int2(e, src[e]); }
}

// ---------------- per-dst rank-1 accumulation + inline edge-MLP, cin=16 (R7 proven) ----------------

__global__ __launch_bounds__(64) void k_accK1(const float* __restrict__ x,
    const int* __restrict__ offs, const int2* __restrict__ elist2,
    const float* __restrict__ ea, const float* __restrict__ w1, const float* __restrict__ b1,
    unsigned short* __restrict__ K1, float* __restrict__ XS, int v0){
  int v = v0 + blockIdx.x;
  int L = threadIdx.x;
  int cg = L & 3, mg = L >> 2;
  int i0 = cg << 2;
  float w1c0 = w1[L], w1c1 = w1[64+L], w1c2 = w1[128+L], w1c3 = w1[192+L];
  float b1c = b1[L];
  __shared__ float sh[2][64];
  float acc[4][4];
  #pragma unroll
  for(int j=0;j<4;j++)
    #pragma unroll
    for(int c=0;c<4;c++) acc[j][c]=0.f;
  float4 xs = make_float4(0.f,0.f,0.f,0.f);
  int p0 = offs[v], p1 = offs[v+1];
  float4 a_nxt = make_float4(0.f,0.f,0.f,0.f);
  float4 x_nxt = make_float4(0.f,0.f,0.f,0.f);
  if(p0 < p1){
    int2 es = elist2[p0];
    a_nxt = *(const float4*)(ea + (size_t)es.x*4);
    x_nxt = *(const float4*)(x + (size_t)es.y*16 + i0);
  }
  for(int p=p0;p<p1;p++){
    int buf = (p-p0)&1;
    float4 xv = x_nxt;
    float4 av = a_nxt;
    float hv = fmaxf(b1c + av.x*w1c0 + av.y*w1c1 + av.z*w1c2 + av.w*w1c3, 0.f);
    sh[buf][L] = hv;
    __syncthreads();
    if(p+1<p1){
      int2 es = elist2[p+1];
      a_nxt = *(const float4*)(ea + (size_t)es.x*4);
      x_nxt = *(const float4*)(x + (size_t)es.y*16 + i0);
    }
    xs.x += xv.x; xs.y += xv.y; xs.z += xv.z; xs.w += xv.w;
    #pragma unroll
    for(int j=0;j<4;j++){
      float hm = sh[buf][mg + 16*j];
      acc[j][0] += hm*xv.x; acc[j][1] += hm*xv.y;
      acc[j][2] += hm*xv.z; acc[j][3] += hm*xv.w;
    }
  }
  int r = blockIdx.x;
  int rt = r >> 4, lrow = r & 15;
  #pragma unroll
  for(int j=0;j<4;j++){
    int m = mg + 16*j;
    size_t sidx = ((size_t)(rt*32 + (m>>1)))*512
                + (size_t)lrow*32 + (m&1)*16 + cg*4;
    ushort4 u;
    u.x=f2b(acc[j][0]); u.y=f2b(acc[j][1]); u.z=f2b(acc[j][2]); u.w=f2b(acc[j][3]);
    *(ushort4*)(K1 + sidx) = u;
  }
  if(mg==0) *(float4*)(XS + (size_t)v*64 + i0) = xs;
}

// ---------------- per-dst rank-1 accumulation + inline edge-MLP, cin=64 (R7 proven) ----------------

__global__ __launch_bounds__(64) void k_accK2(const float* __restrict__ x1,
    const int* __restrict__ offs, const int2* __restrict__ elist2,
    const float* __restrict__ ea, const float* __restrict__ w1, const float* __restrict__ b1,
    unsigned short* __restrict__ K, float* __restrict__ XS, int v0){
  int v = v0 + blockIdx.x;
  int L = threadIdx.x;
  int cg = L & 7, mg = L >> 3;
  int i0 = cg << 3;
  float w1c0 = w1[L], w1c1 = w1[64+L], w1c2 = w1[128+L], w1c3 = w1[192+L];
  float b1c = b1[L];
  __shared__ float sh[2][64];
  float acc[8][8];
  #pragma unroll
  for(int j=0;j<8;j++)
    #pragma unroll
    for(int c=0;c<8;c++) acc[j][c]=0.f;
  float4 xs0 = make_float4(0.f,0.f,0.f,0.f);
  float4 xs1 = make_float4(0.f,0.f,0.f,0.f);
  int p0 = offs[v], p1 = offs[v+1];
  float4 a_nxt = make_float4(0.f,0.f,0.f,0.f);
  float4 x_nxt0 = make_float4(0.f,0.f,0.f,0.f);
  float4 x_nxt1 = make_float4(0.f,0.f,0.f,0.f);
  if(p0 < p1){
    int2 es = elist2[p0];
    a_nxt = *(const float4*)(ea + (size_t)es.x*4);
    const float* xr = x1 + (size_t)es.y*64 + i0;
    x_nxt0 = *(const float4*)xr;
    x_nxt1 = *(const float4*)(xr+4);
  }
  for(int p=p0;p<p1;p++){
    int buf = (p-p0)&1;
    float4 xv0 = x_nxt0, xv1 = x_nxt1;
    float4 av = a_nxt;
    float hv = fmaxf(b1c + av.x*w1c0 + av.y*w1c1 + av.z*w1c2 + av.w*w1c3, 0.f);
    sh[buf][L] = hv;
    __syncthreads();
    if(p+1<p1){
      int2 es = elist2[p+1];
      a_nxt = *(const float4*)(ea + (size_t)es.x*4);
      const float* xr = x1 + (size_t)es.y*64 + i0;
      x_nxt0 = *(const float4*)xr;
      x_nxt1 = *(const float4*)(xr+4);
    }
    xs0.x += xv0.x; xs0.y += xv0.y; xs0.z += xv0.z; xs0.w += xv0.w;
    xs1.x += xv1.x; xs1.y += xv1.y; xs1.z += xv1.z; xs1.w += xv1.w;
    float4 h4a = *(float4*)&sh[buf][mg*8];
    float4 h4b = *(float4*)&sh[buf][mg*8+4];
    #pragma unroll
    for(int jj=0;jj<2;jj++){
      float4 h4 = jj? h4b : h4a;
      #pragma unroll
      for(int tq=0;tq<4;tq++){
        int j = jj*4+tq;
        float hm = (tq==0)?h4.x:(tq==1)?h4.y:(tq==2)?h4.z:h4.w;
        acc[j][0] += hm*xv0.x; acc[j][1] += hm*xv0.y;
        acc[j][2] += hm*xv0.z; acc[j][3] += hm*xv0.w;
        acc[j][4] += hm*xv1.x; acc[j][5] += hm*xv1.y;
        acc[j][6] += hm*xv1.z; acc[j][7] += hm*xv1.w;
      }
    }
  }
  int r = blockIdx.x;
  int rt = r >> 4, lrow = r & 15;
  #pragma unroll
  for(int j=0;j<8;j++){
    int m = mg*8 + j;
    size_t sidx = ((size_t)(rt*128 + m*2 + (cg>>2)))*512
                + (size_t)lrow*32 + (cg&3)*8;
    u16x8 u;
    #pragma unroll
    for(int c=0;c<8;c++) u[c] = f2b(acc[j][c]);
    *(u16x8*)(K + sidx) = u;
  }
  if(mg==0){
    *(float4*)(XS + (size_t)v*64 + i0)     = xs0;
    *(float4*)(XS + (size_t)v*64 + i0 + 4) = xs1;
  }
}

// ---------------- layer-1 full-K GEMM + fused epilogue -> x1 (no P, no reduce) ----------------
// 512 thr = 8 waves; ALL of Bt1 (128 KB) staged in LDS; wave w computes row-tile
// bx*8+w over full K=1024 (TSTEPS=32), then epilogue: relu((acc + XS*b2)/deg + x@root + bias).

__global__ __launch_bounds__(512) void k_gemmS1F(const unsigned short* __restrict__ A,
    const unsigned short* __restrict__ Bt,
    const float* __restrict__ XS, const float* __restrict__ eb,
    const float* __restrict__ xp, const float* __restrict__ rw,
    const float* __restrict__ bw, const int* __restrict__ offs,
    float* __restrict__ x1out, int ntiles, int v0){
  __shared__ unsigned short Bs[65536];   // 128 KB = entire Bt1
  int tid = threadIdx.x;
  int lane = tid & 63;
  int w = tid >> 6;

  #pragma unroll
  for(int it=0; it<16; it++)
    *(short8*)(Bs + it*4096 + tid*8) = *(const short8*)(Bt + it*4096 + tid*8);
  __syncthreads();

  int lrt = blockIdx.x*8 + w;
  if(lrt >= ntiles) return;   // after the only barrier -> safe

  int lperm = (lane & 15)*32 + (lane >> 4)*8;
  const unsigned short* Ap = A + (((size_t)lrt*32) << 9) + lperm;
  const unsigned short* BsL = Bs + lperm;

  float4v acc0{}, acc1{}, acc2{}, acc3{};
  short8 ab[4];
  #pragma unroll
  for(int t=0;t<4;t++) ab[t] = ntload(Ap + t*512);

  #pragma unroll
  for(int t=0;t<32;t++){
    short8 a  = ab[t&3];
    short8 b0 = *(const short8*)(BsL + (0*32+t)*512);
    short8 b1 = *(const short8*)(BsL + (1*32+t)*512);
    short8 b2 = *(const short8*)(BsL + (2*32+t)*512);
    short8 b3 = *(const short8*)(BsL + (3*32+t)*512);
    acc0 = __builtin_amdgcn_mfma_f32_16x16x32_bf16(a, b0, acc0, 0,0,0);
    acc1 = __builtin_amdgcn_mfma_f32_16x16x32_bf16(a, b1, acc1, 0,0,0);
    acc2 = __builtin_amdgcn_mfma_f32_16x16x32_bf16(a, b2, acc2, 0,0,0);
    acc3 = __builtin_amdgcn_mfma_f32_16x16x32_bf16(a, b3, acc3, 0,0,0);
    if(t+4 < 32) ab[t&3] = ntload(Ap + (t+4)*512);
  }

  // fused epilogue: lane owns rows quad*4+reg (4) x cols ct*16+lrow (4)
  int lrow = lane & 15, quad = lane >> 4;
  int vb = v0 + lrt*16 + quad*4;
  float s[4][4], tt[4][4];
  #pragma unroll
  for(int reg=0; reg<4; reg++){
    s[reg][0]=acc0[reg]; s[reg][1]=acc1[reg]; s[reg][2]=acc2[reg]; s[reg][3]=acc3[reg];
    tt[reg][0]=0.f; tt[reg][1]=0.f; tt[reg][2]=0.f; tt[reg][3]=0.f;
  }
  #pragma unroll 4
  for(int i=0;i<16;i++){
    float e0 = eb[i*64 +  0 + lrow], e1 = eb[i*64 + 16 + lrow];
    float e2 = eb[i*64 + 32 + lrow], e3 = eb[i*64 + 48 + lrow];
    float r0 = rw[i*64 +  0 + lrow], r1 = rw[i*64 + 16 + lrow];
    float r2 = rw[i*64 + 32 + lrow], r3 = rw[i*64 + 48 + lrow];
    #pragma unroll
    for(int reg=0; reg<4; reg++){
      float xsv = XS[(size_t)(vb+reg)*64 + i];
      float xpv = xp[(size_t)(vb+reg)*16 + i];
      s[reg][0] += xsv*e0; s[reg][1] += xsv*e1; s[reg][2] += xsv*e2; s[reg][3] += xsv*e3;
      tt[reg][0] += xpv*r0; tt[reg][1] += xpv*r1; tt[reg][2] += xpv*r2; tt[reg][3] += xpv*r3;
    }
  }
  float bw0 = bw[lrow], bw1 = bw[16+lrow], bw2 = bw[32+lrow], bw3 = bw[48+lrow];
  #pragma unroll
  for(int reg=0; reg<4; reg++){
    int v = vb + reg;
    float dg = fmaxf((float)(offs[v+1]-offs[v]), 1.f);
    float inv = 1.f/dg;
    float* xr = x1out + (size_t)v*64 + lrow;
    xr[ 0] = fmaxf(s[reg][0]*inv + tt[reg][0] + bw0, 0.f);
    xr[16] = fmaxf(s[reg][1]*inv + tt[reg][1] + bw1, 0.f);
    xr[32] = fmaxf(s[reg][2]*inv + tt[reg][2] + bw2, 0.f);
    xr[48] = fmaxf(s[reg][3]*inv + tt[reg][3] + bw3, 0.f);
  }
}

// ---------------- split-K GEMM, 128 rows/block, B-slice staged in LDS (layer 2) ----------------

template<int KT32, int TSTEPS>
__global__ __launch_bounds__(512) void k_gemmS(const unsigned short* __restrict__ A,
    const unsigned short* __restrict__ Bt, float* __restrict__ P,
    int ntiles, int rowsChunk){
  __shared__ unsigned short Bs[4*TSTEPS*512];
  int tid = threadIdx.x;
  int lane = tid & 63;
  int w = tid >> 6;
  int s = blockIdx.y;
  int kbase = s*TSTEPS;

  constexpr int NT = 4*TSTEPS;
  constexpr int PERW = NT/8;
  #pragma unroll
  for(int it=0; it<PERW; it++){
    int g = w*PERW + it;
    int ct = g / TSTEPS, t = g - ct*TSTEPS;
    *(short8*)(Bs + (size_t)g*512 + lane*8) =
        *(const short8*)(Bt + (((size_t)ct*KT32 + kbase + t) << 9) + lane*8);
  }
  __syncthreads();

  int lrt = blockIdx.x*8 + w;
  if(lrt >= ntiles) return;

  int lperm = (lane & 15)*32 + (lane >> 4)*8;
  const unsigned short* Ap = A + (((size_t)lrt*KT32 + kbase) << 9) + lperm;
  const unsigned short* BsL = Bs + lperm;

  float4v acc0{}, acc1{}, acc2{}, acc3{};
  short8 ab[4];
  #pragma unroll
  for(int t=0;t<4;t++) ab[t] = ntload(Ap + t*512);

  #pragma unroll
  for(int t=0;t<TSTEPS;t++){
    short8 a  = ab[t&3];
    short8 b0 = *(const short8*)(BsL + (0*TSTEPS+t)*512);
    short8 b1 = *(const short8*)(BsL + (1*TSTEPS+t)*512);
    short8 b2 = *(const short8*)(BsL + (2*TSTEPS+t)*512);
    short8 b3 = *(const short8*)(BsL + (3*TSTEPS+t)*512);
    acc0 = __builtin_amdgcn_mfma_f32_16x16x32_bf16(a, b0, acc0, 0,0,0);
    acc1 = __builtin_amdgcn_mfma_f32_16x16x32_bf16(a, b1, acc1, 0,0,0);
    acc2 = __builtin_amdgcn_mfma_f32_16x16x32_bf16(a, b2, acc2, 0,0,0);
    acc3 = __builtin_amdgcn_mfma_f32_16x16x32_bf16(a, b3, acc3, 0,0,0);
    if(t+4 < TSTEPS) ab[t&3] = ntload(Ap + (t+4)*512);
  }

  int lrow = lane & 15, quad = lane >> 4;
  float* Pr = P + ((size_t)s*rowsChunk + lrt*16 + quad*4)*64 + lrow;
  #pragma unroll
  for(int reg=0;reg<4;reg++){
    Pr[(size_t)reg*64 +  0] = acc0[reg];
    Pr[(size_t)reg*64 + 16] = acc1[reg];
    Pr[(size_t)reg*64 + 32] = acc2[reg];
    Pr[(size_t)reg*64 + 48] = acc3[reg];
  }
}

// ---------------- layer-2 reduction + epilogue + fused readout ----------------

template<int SPLIT>
__global__ __launch_bounds__(256) void k_red2_ro(const float* __restrict__ P, int rows, int v0,
    const float* __restrict__ XS, const float* __restrict__ b2, const float* __restrict__ x1,
    const float* __restrict__ root, const float* __restrict__ bias, const int* __restrict__ offs,
    const float* __restrict__ lw1, const float* __restrict__ lb1,
    const float* __restrict__ lw2, const float* __restrict__ lb2,
    float* __restrict__ out){
  __shared__ float row[16][68];
  __shared__ float hjs[16][8];
  int tid = threadIdx.x;
  int idx = blockIdx.x*256 + tid;
  int r = idx >> 4, og = (idx & 15) << 2;
  int n = tid >> 4;
  int nbase = blockIdx.x*16;
  int ninblk = rows - nbase; if(ninblk > 16) ninblk = 16;

  float4 o = make_float4(0.f,0.f,0.f,0.f);
  if(r < rows){
    int vg = v0 + r;
    float4 s = make_float4(0.f,0.f,0.f,0.f);
    #pragma unroll
    for(int z=0; z<SPLIT; z++){
      float4 p = *(const float4*)(P + ((size_t)z*rows + r)*64 + og);
      s.x += p.x; s.y += p.y; s.z += p.z; s.w += p.w;
    }
    #pragma unroll
    for(int i=0;i<64;i++){
      float xsv = XS[(size_t)vg*64 + i];
      float4 b = *(const float4*)(b2 + i*64 + og);
      s.x += xsv*b.x; s.y += xsv*b.y; s.z += xsv*b.z; s.w += xsv*b.w;
    }
    float4 rt = make_float4(0.f,0.f,0.f,0.f);
    #pragma unroll
    for(int i=0;i<64;i++){
      float xv = x1[(size_t)vg*64 + i];
      float4 wv = *(const float4*)(root + i*64 + og);
      rt.x += xv*wv.x; rt.y += xv*wv.y; rt.z += xv*wv.z; rt.w += xv*wv.w;
    }
    float c = (float)(offs[vg+1]-offs[vg]); c = fmaxf(c, 1.f);
    float inv = 1.f/c;
    float4 bi = *(const float4*)(bias + og);
    o.x = fmaxf(s.x*inv + rt.x + bi.x, 0.f);
    o.y = fmaxf(s.y*inv + rt.y + bi.y, 0.f);
    o.z = fmaxf(s.z*inv + rt.z + bi.z, 0.f);
    o.w = fmaxf(s.w*inv + rt.w + bi.w, 0.f);
  }
  *(float4*)&row[n][og] = o;
  __syncthreads();
  if(tid < 128){
    int n2 = tid >> 3, j = tid & 7;
    if(n2 < ninblk){
      float a = lb1[j];
      #pragma unroll
      for(int i=0;i<64;i++) a += row[n2][i]*lw1[i*8+j];
      hjs[n2][j] = fmaxf(a, 0.f)*lw2[j];
    }
  }
  __syncthreads();
  if(tid < 16 && tid < ninblk){
    float s = lb2[0];
    #pragma unroll
    for(int j=0;j<8;j++) s += hjs[tid][j];
    out[v0 + nbase + tid] = s;
  }
}

// ---------------- host ----------------

extern "C" void kernel_launch(void* const* d_in, const int* in_sizes, int n_in,
                              void* d_out, int out_size, void* d_ws, size_t ws_size,
                              hipStream_t stream) {
  const float* x      = (const float*)d_in[0];
  const int*   ei     = (const int*)d_in[1];
  const float* ea     = (const float*)d_in[2];
  const float* nn1_w1 = (const float*)d_in[3];
  const float* nn1_b1 = (const float*)d_in[4];
  const float* nn1_w2 = (const float*)d_in[5];
  const float* nn1_b2 = (const float*)d_in[6];
  const float* root1  = (const float*)d_in[7];
  const float* bias1  = (const float*)d_in[8];
  const float* nn2_w1 = (const float*)d_in[9];
  const float* nn2_b1 = (const float*)d_in[10];
  const float* nn2_w2 = (const float*)d_in[11];
  const float* nn2_b2 = (const float*)d_in[12];
  const float* root2  = (const float*)d_in[13];
  const float* bias2  = (const float*)d_in[14];
  const float* lin1_w = (const float*)d_in[15];
  const float* lin1_b = (const float*)d_in[16];
  const float* lin2_w = (const float*)d_in[17];
  const float* lin2_b = (const float*)d_in[18];
  float* out = (float*)d_out;

  const int* srcIdx = ei;
  const int* dstIdx = ei + EE;

  char* w = (char*)d_ws;
  size_t off = 0;
  auto alloc = [&](size_t bytes)->void*{
    void* p = w + off;
    off = (off + bytes + 255) & ~(size_t)255;
    return p;
  };
  int*            cnt    = (int*)           alloc((size_t)NN*4);
  int*            offs   = (int*)           alloc((size_t)(NN+1)*4);
  int*            cursor = (int*)           alloc((size_t)NN*4);
  int2*           elist2 = (int2*)          alloc((size_t)EE*8);
  float*          XS     = (float*)         alloc((size_t)NN*64*4);
  float*          x1     = (float*)         alloc((size_t)NN*64*4);
  unsigned short* Bt1    = (unsigned short*)alloc((size_t)64*1024*2);
  unsigned short* Bt2    = (unsigned short*)alloc((size_t)64*4096*2);
  size_t fixedBytes = off;
  size_t R = (ws_size > fixedBytes) ? (ws_size - fixedBytes) : 0;

  const int S2 = 8;   // layer2: KT32=128, TSTEPS=16 (64 KB LDS B-slice)
  size_t needSingle = (size_t)(NN/16)*128*1024 + (size_t)S2*NN*64*4;
  bool single = (R >= needSingle + 4096);

  k_prep   <<<1320, 256, 0, stream>>>(nn1_w2, Bt1, nn2_w2, Bt2, cnt);
  k_hist   <<<(EE+255)/256, 256, 0, stream>>>(dstIdx, cnt);
  k_scan   <<<1, 1024, 0, stream>>>(cnt, offs, cursor);
  k_scatter<<<(EE+255)/256, 256, 0, stream>>>(dstIdx, srcIdx, cursor, elist2);

  if(single){
    unsigned short* Kbuf = (unsigned short*)(w + off);
    float* P = (float*)(w + off + (size_t)(NN/16)*128*1024);
    int ntiles = NN/16;                 // 625
    int gx = (ntiles + 7)/8;            // 79

    k_accK1 <<<NN, 64, 0, stream>>>(x, offs, elist2, ea, nn1_w1, nn1_b1, Kbuf, XS, 0);
    k_gemmS1F<<<gx, 512, 0, stream>>>(Kbuf, Bt1, XS, nn1_b2, x, root1, bias1, offs,
                                      x1, ntiles, 0);
    k_accK2 <<<NN, 64, 0, stream>>>(x1, offs, elist2, ea, nn2_w1, nn2_b1, Kbuf, XS, 0);
    k_gemmS<128,16><<<dim3(gx, S2), 512, 0, stream>>>(Kbuf, Bt2, P, ntiles, NN);
    k_red2_ro<S2><<<(NN+15)/16, 256, 0, stream>>>(P, NN, 0, XS, nn2_b2, x1, root2, bias2, offs,
                                                   lin1_w, lin1_b, lin2_w, lin2_b, out);
  } else {
    long long C2 = (long long)(R / (8192 + S2*256));
    long long C1 = (long long)(R / 2048);
    if(C2 > NN) C2 = NN; if(C1 > NN) C1 = NN;
    C2 &= ~127LL; C1 &= ~127LL;
    if(C2 < 128) C2 = 128; if(C1 < 128) C1 = 128;
    unsigned short* Kbuf = (unsigned short*)(w + off);
    {
      for(long long v0=0; v0<NN; v0+=C1){
        int rows = (int)((NN - v0 < C1) ? (NN - v0) : C1);
        int nt = rows/16, gx = (nt + 7)/8;
        k_accK1<<<rows, 64, 0, stream>>>(x, offs, elist2, ea, nn1_w1, nn1_b1, Kbuf, XS, (int)v0);
        k_gemmS1F<<<gx, 512, 0, stream>>>(Kbuf, Bt1, XS, nn1_b2, x, root1, bias1, offs,
                                          x1, nt, (int)v0);
      }
    }
    {
      float* P = (float*)(w + off + (size_t)C2*8192);
      for(long long v0=0; v0<NN; v0+=C2){
        int rows = (int)((NN - v0 < C2) ? (NN - v0) : C2);
        int nt = rows/16, gx = (nt + 7)/8;
        k_accK2<<<rows, 64, 0, stream>>>(x1, offs, elist2, ea, nn2_w1, nn2_b1, Kbuf, XS, (int)v0);
        k_gemmS<128,16><<<dim3(gx, S2), 512, 0, stream>>>(Kbuf, Bt2, P, nt, rows);
        k_red2_ro<S2><<<(rows+15)/16, 256, 0, stream>>>(P, rows, (int)v0, XS, nn2_b2, x1,
                                                         root2, bias2, offs,
                                                         lin1_w, lin1_b, lin2_w, lin2_b, out);
      }
    }
  }
}